// Round 1
// 74.490 us; speedup vs baseline: 1.0166x; 1.0166x over previous
//
#include <hip/hip_runtime.h>

// ConjunctionLayer: out[b,j] = -1 / (-1 + sum_i log(1 - (1-x[b,i]) * W[j,i]))
// B=4096, INPUT_DIM=512, N=128, fp32.
//
// R4: attack register-pressure pathology suspected from R2/R3 history
// (indexed local arrays w[32]/u[32] = 128 held VGPRs -> scratch/serial-VMEM).
//   * z = 1-(1-x)*W  ==  fma(W, x-1, 1.0): eliminates u[] entirely
//     (inline-const 1.0 is free in the fma) -> 64 held VGPRs, not 128.
//   * xm = x-1 staged ONCE per block into LDS (32 KB, cooperative,
//     coalesced dwordx4); hot loop reads wave-uniform ds_read_b128
//     (broadcast, conflict-free, lgkm-counted) instead of per-bi global.
//   * W fragment held as 16 NAMED v4f SSA values -> SROA cannot fail,
//     guaranteed registers (rule: runtime-indexed locals go to scratch).
//   * __launch_bounds__(512,4): VGPR cap 128 -> 2 blocks/CU (4 waves/SIMD),
//     double R3b's occupancy; ~120 est. live regs.
// Mapping unchanged: lane <-> j (64 j per wave, h = j-half), wave <-> K-chunk
// (8 waves x 64 i), 16 b per block; product-of-16 z -> one v_log_f32
// (z in (0.5,1] so partial product >= 0.5^16 stays normal fp32).

typedef float v2f __attribute__((ext_vector_type(2)));
typedef float v4f __attribute__((ext_vector_type(4)));

constexpr int IDIM  = 512;
constexpr int NOUT  = 128;
constexpr int BTOT  = 4096;
constexpr int KC    = 64;            // i per wave
constexpr int NB    = 16;            // b per block
constexpr int GB    = BTOT / NB;     // 256 b-groups
constexpr float LN2 = 0.69314718055994530942f;

// One log per 16 i. xq: wave-uniform LDS pointer to xm[b, i0:i0+16]
// (4 x ds_read_b128 broadcast). wa..wd: per-lane W[j, i0:i0+16] in SSA regs.
__device__ __forceinline__ float grouplog(const v4f* __restrict__ xq,
                                          v4f wa, v4f wb, v4f wc, v4f wd) {
    v4f t0 = xq[0], t1 = xq[1], t2 = xq[2], t3 = xq[3];
    v4f z0 = wa * t0 + 1.0f;          // v_pk_fma_f32: z = W*(x-1) + 1
    v4f z1 = wb * t1 + 1.0f;
    v4f z2 = wc * t2 + 1.0f;
    v4f z3 = wd * t3 + 1.0f;
    v4f p  = (z0 * z1) * (z2 * z3);
    float m = (p.x * p.y) * (p.z * p.w);
    return __builtin_amdgcn_logf(m);  // v_log_f32 (log2); rescale by ln2 at end
}

__global__ __launch_bounds__(512, 4)
void conj_kernel(const float* __restrict__ x,
                 const float* __restrict__ W,
                 float* __restrict__ out)
{
    __shared__ __align__(16) float s_xm[NB * IDIM];   // 32 KB: x-1 tile
    __shared__ __align__(16) float s_p[NB * 8 * 64];  // 32 KB: partial log-sums

    const int tid  = threadIdx.x;
    const int lane = tid & 63;
    const int wv   = __builtin_amdgcn_readfirstlane(tid >> 6);   // 0..7, SGPR
    const int h    = blockIdx.x >> 8;        // j-half; h-pairs 256 apart -> same XCD
    const int bg   = blockIdx.x & (GB - 1);
    const int b0   = bg * NB;
    const int j    = h * 64 + lane;
    const int k0   = wv * KC;

    // Loop-invariant W fragment: W[j, k0:k0+64] as 16 named v4f (64 VGPRs).
    const v4f* wp = (const v4f*)(W + (size_t)j * IDIM + k0);
    v4f w0  = wp[0],  w1  = wp[1],  w2  = wp[2],  w3  = wp[3];
    v4f w4  = wp[4],  w5  = wp[5],  w6  = wp[6],  w7  = wp[7];
    v4f w8  = wp[8],  w9  = wp[9],  w10 = wp[10], w11 = wp[11];
    v4f w12 = wp[12], w13 = wp[13], w14 = wp[14], w15 = wp[15];

    // Stage xm = x - 1 into LDS: 16 b x 512 i = 2048 v4f over 512 threads,
    // coalesced global_load_dwordx4 + pk_add + ds_write_b128.
    {
        const v4f* xg = (const v4f*)(x + (size_t)b0 * IDIM);
        v4f* xs = (v4f*)s_xm;
        #pragma unroll
        for (int q = 0; q < 4; ++q) {
            v4f t = xg[tid + q * 512];
            xs[tid + q * 512] = t - 1.0f;
        }
    }
    __syncthreads();

    for (int bi = 0; bi < NB; ++bi) {
        const v4f* xq = (const v4f*)(s_xm + bi * IDIM + k0);  // wave-uniform
        float s = grouplog(xq + 0,  w0,  w1,  w2,  w3)
                + grouplog(xq + 4,  w4,  w5,  w6,  w7)
                + grouplog(xq + 8,  w8,  w9,  w10, w11)
                + grouplog(xq + 12, w12, w13, w14, w15);
        s_p[bi * 512 + wv * 64 + lane] = s;    // lanes consecutive: no conflict
    }
    __syncthreads();

    // Reduce the 8 K-chunks, finalize, coalesced store.
    #pragma unroll
    for (int r = 0; r < (NB * 64) / 512; ++r) {   // 2 outputs/thread
        const int idx = tid + r * 512;
        const int bi  = idx >> 6;
        const int l   = idx & 63;
        float sum = 0.0f;
        #pragma unroll
        for (int wq = 0; wq < 8; ++wq)
            sum += s_p[bi * 512 + wq * 64 + l];   // stride 64: conflict-free
        out[(size_t)(b0 + bi) * NOUT + h * 64 + l] = 1.0f / (1.0f - LN2 * sum);
    }
}

extern "C" void kernel_launch(void* const* d_in, const int* in_sizes, int n_in,
                              void* d_out, int out_size, void* d_ws, size_t ws_size,
                              hipStream_t stream) {
    const float* x = (const float*)d_in[0];   // (4096, 512) fp32
    const float* W = (const float*)d_in[1];   // (128, 512) fp32
    float* out = (float*)d_out;               // (4096, 128) fp32

    dim3 grid(2 * GB);                        // 512 blocks (j-half major)
    dim3 block(512);                          // 8 waves
    hipLaunchKernelGGL(conj_kernel, grid, block, 0, stream, x, W, out);
}